// Round 2
// baseline (420.841 us; speedup 1.0000x reference)
//
#include <hip/hip_runtime.h>
#include <hip/hip_bf16.h>

typedef _Float16 f16x8 __attribute__((ext_vector_type(8)));
typedef float    f32x4 __attribute__((ext_vector_type(4)));

#define B_SZ 512
#define T_SZ 2048
#define D_SZ 256
#define TCHUNK 32
#define NCHUNK (T_SZ / TCHUNK)   // 64

// ---------- kernel 1: W_eff[e,k] = sum_d Wa[e,d]*Wi[d,k];  b_eff[e] = Wa[e,:]@(bi+bh) + ba[e]
__global__ __launch_bounds__(256) void prep_kernel(
    const float* __restrict__ Wa, const float* __restrict__ Wi,
    const float* __restrict__ bi, const float* __restrict__ bh,
    const float* __restrict__ ba,
    _Float16* __restrict__ Weff, float* __restrict__ beff)
{
    int e = blockIdx.x;      // output row (256)
    int d = threadIdx.x;     // output col (256)
    float a0 = 0.f, a1 = 0.f, a2 = 0.f, a3 = 0.f;
    #pragma unroll 4
    for (int k = 0; k < 256; k += 4) {
        a0 = fmaf(Wa[e*256 + k    ], Wi[(k    )*256 + d], a0);
        a1 = fmaf(Wa[e*256 + k + 1], Wi[(k + 1)*256 + d], a1);
        a2 = fmaf(Wa[e*256 + k + 2], Wi[(k + 2)*256 + d], a2);
        a3 = fmaf(Wa[e*256 + k + 3], Wi[(k + 3)*256 + d], a3);
    }
    Weff[e*256 + d] = (_Float16)((a0 + a1) + (a2 + a3));

    // bias reduce: wave-parallel
    __shared__ float red[4];
    float s = Wa[e*256 + d] * (bi[d] + bh[d]);
    s += __shfl_down(s, 32, 64);
    s += __shfl_down(s, 16, 64);
    s += __shfl_down(s,  8, 64);
    s += __shfl_down(s,  4, 64);
    s += __shfl_down(s,  2, 64);
    s += __shfl_down(s,  1, 64);
    if ((d & 63) == 0) red[d >> 6] = s;
    __syncthreads();
    if (d == 0) beff[e] = ba[e] + ((red[0] + red[1]) + (red[2] + red[3]));
}

// ---------- kernel 2: fused GEMM(x, W_eff^T) + sigmoid + sum_t attn*x -> ao (B,256)
// one block per batch; 8 waves x 32 output cols. x staged fp32 into double-buffered
// LDS via global_load_lds (linear dest, inverse-swizzled global source, swizzled reads).
__global__ __launch_bounds__(512, 4) void attn_kernel(
    const float* __restrict__ x,          // (B, T, D)
    const _Float16* __restrict__ Weff,    // (256, 256) row-major [e][k]
    const float* __restrict__ beff,       // (256)
    float* __restrict__ ao)               // (B, 256)
{
    const int b    = blockIdx.x;
    const int tid  = threadIdx.x;
    const int wave = tid >> 6;
    const int lane = tid & 63;
    const int l15  = lane & 15;
    const int lq   = lane >> 4;

    __shared__ float xs[2][TCHUNK * 256];   // 2 x 32 KB fp32, swizzle byte ^= (row&7)<<4

    // B fragments: W_eff[n][k], 8 contiguous k per lane (layout verified in round 1)
    f16x8 bfrag[2][8];
    #pragma unroll
    for (int ct = 0; ct < 2; ++ct) {
        int col = wave*32 + ct*16 + l15;
        #pragma unroll
        for (int ks = 0; ks < 8; ++ks) {
            int k0 = ks*32 + lq*8;
            bfrag[ct][ks] = *reinterpret_cast<const f16x8*>(&Weff[col*256 + k0]);
        }
    }
    float bcol0 = beff[wave*32 + l15];
    float bcol1 = beff[wave*32 + 16 + l15];

    const float* xb = x + (size_t)b * T_SZ * D_SZ;

    // each wave stages rows wave*4 .. wave*4+3 of the 32-row chunk (1 row = 1 KB = 1 instr)
    #define STAGE(dstbuf, c)                                                          \
        {                                                                             \
            _Pragma("unroll")                                                         \
            for (int i = 0; i < 4; ++i) {                                             \
                int rw = wave*4 + i;                                                  \
                int gcol = (lane*16) ^ ((rw & 7) << 4);                               \
                const char* srcp = (const char*)(xb + (size_t)((c)*TCHUNK + rw)*256) + gcol; \
                char* dstp = (char*)(&xs[dstbuf][0]) + rw*1024;                       \
                __builtin_amdgcn_global_load_lds(                                     \
                    (const __attribute__((address_space(1))) void*)srcp,              \
                    (__attribute__((address_space(3))) void*)dstp, 16, 0, 0);         \
            }                                                                         \
        }

    float ao_acc0 = 0.f, ao_acc1 = 0.f;

    STAGE(0, 0);   // prologue
    int cur = 0;

    for (int c = 0; c < NCHUNK; ++c) {
        if (c + 1 < NCHUNK) {
            STAGE(cur ^ 1, c + 1);
            asm volatile("s_waitcnt vmcnt(4)" ::: "memory");   // cur buffer's 4 loads done
        } else {
            asm volatile("s_waitcnt vmcnt(0)" ::: "memory");
        }
        __builtin_amdgcn_s_barrier();   // all waves' stage of cur complete

        const char* buf = (const char*)(&xs[cur][0]);

        #pragma unroll
        for (int rt = 0; rt < 2; ++rt) {
            const int arow = rt*16 + l15;
            const int aswz = (arow & 7) << 4;
            const int abase = arow*1024;
            f32x4 acc0 = {0.f, 0.f, 0.f, 0.f};
            f32x4 acc1 = {0.f, 0.f, 0.f, 0.f};
            #pragma unroll
            for (int ks = 0; ks < 8; ++ks) {
                int cb0 = ks*128 + lq*32;
                f32x4 lo = *reinterpret_cast<const f32x4*>(buf + abase + ((cb0     ) ^ aswz));
                f32x4 hi = *reinterpret_cast<const f32x4*>(buf + abase + ((cb0 + 16) ^ aswz));
                f16x8 a;
                a[0] = (_Float16)lo[0]; a[1] = (_Float16)lo[1];
                a[2] = (_Float16)lo[2]; a[3] = (_Float16)lo[3];
                a[4] = (_Float16)hi[0]; a[5] = (_Float16)hi[1];
                a[6] = (_Float16)hi[2]; a[7] = (_Float16)hi[3];
                acc0 = __builtin_amdgcn_mfma_f32_16x16x32_f16(a, bfrag[0][ks], acc0, 0, 0, 0);
                acc1 = __builtin_amdgcn_mfma_f32_16x16x32_f16(a, bfrag[1][ks], acc1, 0, 0, 0);
            }
            // epilogue: C row = lq*4 + r (+rt*16), col = l15 (+ct*16+wave*32)
            #pragma unroll
            for (int r = 0; r < 4; ++r) {
                int row  = rt*16 + lq*4 + r;
                int rswz = (row & 7) << 4;
                int rb   = row*1024;
                {
                    float s = acc0[r] + bcol0;
                    float attn = __builtin_amdgcn_rcpf(1.f + __expf(-s));
                    int cb = ((wave*32 + l15)*4) ^ rswz;
                    float xv = *reinterpret_cast<const float*>(buf + rb + cb);
                    ao_acc0 = fmaf(attn, xv, ao_acc0);
                }
                {
                    float s = acc1[r] + bcol1;
                    float attn = __builtin_amdgcn_rcpf(1.f + __expf(-s));
                    int cb = ((wave*32 + 16 + l15)*4) ^ rswz;
                    float xv = *reinterpret_cast<const float*>(buf + rb + cb);
                    ao_acc1 = fmaf(attn, xv, ao_acc1);
                }
            }
        }

        asm volatile("s_waitcnt lgkmcnt(0)" ::: "memory");   // all LDS reads landed
        __builtin_amdgcn_s_barrier();                        // safe to overwrite cur next iter
        cur ^= 1;
    }

    // reduce over quarter-wave groups (lanes l, l+16, l+32, l+48 share a column)
    float v = ao_acc0;
    v += __shfl_xor(v, 16, 64);
    v += __shfl_xor(v, 32, 64);
    if (lq == 0) ao[b*256 + wave*32 + l15] = v;
    float w = ao_acc1;
    w += __shfl_xor(w, 16, 64);
    w += __shfl_xor(w, 32, 64);
    if (lq == 0) ao[b*256 + wave*32 + 16 + l15] = w;
    #undef STAGE
}

// ---------- kernel 3: LSTM cell (h0=c0=0 => f gate dead, W_hh dead)
__global__ __launch_bounds__(256) void lstm_kernel(
    const float* __restrict__ ao,        // (B, 256)
    const float* __restrict__ Wih,       // (1024, 256)
    const float* __restrict__ bih,       // (1024)
    const float* __restrict__ bhh,       // (1024)
    float* __restrict__ out)             // h (B*256) | h (B*256) | c (B*256)
{
    int b = blockIdx.x;    // 512
    int j = threadIdx.x;   // 256
    __shared__ float a[256];
    a[j] = ao[b*256 + j];
    __syncthreads();

    float gi = bih[j]       + bhh[j];
    float gg = bih[512 + j] + bhh[512 + j];
    float go = bih[768 + j] + bhh[768 + j];
    const float* wi = Wih + (size_t)j * 256;
    const float* wg = Wih + (size_t)(512 + j) * 256;
    const float* wo = Wih + (size_t)(768 + j) * 256;
    #pragma unroll 4
    for (int k = 0; k < 256; k += 4) {
        f32x4 w1 = *reinterpret_cast<const f32x4*>(wi + k);
        f32x4 w2 = *reinterpret_cast<const f32x4*>(wg + k);
        f32x4 w3 = *reinterpret_cast<const f32x4*>(wo + k);
        #pragma unroll
        for (int q = 0; q < 4; ++q) {
            float av = a[k + q];
            gi = fmaf(w1[q], av, gi);
            gg = fmaf(w2[q], av, gg);
            go = fmaf(w3[q], av, go);
        }
    }
    float ig = 1.f / (1.f + __expf(-gi));
    float g  = tanhf(gg);
    float og = 1.f / (1.f + __expf(-go));
    float cc = ig * g;
    float hh = og * tanhf(cc);
    out[          b*256 + j] = hh;
    out[131072 +  b*256 + j] = hh;
    out[262144 +  b*256 + j] = cc;
}

extern "C" void kernel_launch(void* const* d_in, const int* in_sizes, int n_in,
                              void* d_out, int out_size, void* d_ws, size_t ws_size,
                              hipStream_t stream) {
    const float* x    = (const float*)d_in[0];
    const float* Wi   = (const float*)d_in[1];
    const float* bi   = (const float*)d_in[2];
    // d_in[3] = Wh (dead: h0 = 0)
    const float* bh   = (const float*)d_in[4];
    const float* Wa   = (const float*)d_in[5];
    const float* ba   = (const float*)d_in[6];
    const float* W_ih = (const float*)d_in[7];
    const float* b_ih = (const float*)d_in[8];
    // d_in[9] = W_hh (dead: h0 = 0)
    const float* b_hh = (const float*)d_in[10];

    char* ws = (char*)d_ws;
    _Float16* Weff = (_Float16*)ws;                  // 128 KB
    float*    beff = (float*)(ws + 128*1024);        // 1 KB
    float*    ao   = (float*)(ws + 132*1024);        // 512 KB

    prep_kernel<<<256, 256, 0, stream>>>(Wa, Wi, bi, bh, ba, Weff, beff);
    attn_kernel<<<B_SZ, 512, 0, stream>>>(x, Weff, beff, ao);
    lstm_kernel<<<B_SZ, 256, 0, stream>>>(ao, W_ih, b_ih, b_hh, (float*)d_out);
}

// Round 3
// 295.011 us; speedup vs baseline: 1.4265x; 1.4265x over previous
//
#include <hip/hip_runtime.h>
#include <hip/hip_bf16.h>

typedef _Float16 f16x8 __attribute__((ext_vector_type(8)));
typedef float    f32x4 __attribute__((ext_vector_type(4)));

#define B_SZ 512
#define T_SZ 2048
#define D_SZ 256
#define TCHUNK 32
#define NCHUNK (T_SZ / TCHUNK)   // 64

// ---------- kernel 1: W_eff[e,k] = sum_d Wa[e,d]*Wi[d,k];  b_eff[e] = Wa[e,:]@(bi+bh) + ba[e]
__global__ __launch_bounds__(256) void prep_kernel(
    const float* __restrict__ Wa, const float* __restrict__ Wi,
    const float* __restrict__ bi, const float* __restrict__ bh,
    const float* __restrict__ ba,
    _Float16* __restrict__ Weff, float* __restrict__ beff)
{
    int e = blockIdx.x;      // output row (256)
    int d = threadIdx.x;     // output col (256)
    float a0 = 0.f, a1 = 0.f, a2 = 0.f, a3 = 0.f;
    #pragma unroll 4
    for (int k = 0; k < 256; k += 4) {
        a0 = fmaf(Wa[e*256 + k    ], Wi[(k    )*256 + d], a0);
        a1 = fmaf(Wa[e*256 + k + 1], Wi[(k + 1)*256 + d], a1);
        a2 = fmaf(Wa[e*256 + k + 2], Wi[(k + 2)*256 + d], a2);
        a3 = fmaf(Wa[e*256 + k + 3], Wi[(k + 3)*256 + d], a3);
    }
    Weff[e*256 + d] = (_Float16)((a0 + a1) + (a2 + a3));

    __shared__ float red[4];
    float s = Wa[e*256 + d] * (bi[d] + bh[d]);
    s += __shfl_down(s, 32, 64);
    s += __shfl_down(s, 16, 64);
    s += __shfl_down(s,  8, 64);
    s += __shfl_down(s,  4, 64);
    s += __shfl_down(s,  2, 64);
    s += __shfl_down(s,  1, 64);
    if ((d & 63) == 0) red[d >> 6] = s;
    __syncthreads();
    if (d == 0) beff[e] = ba[e] + ((red[0] + red[1]) + (red[2] + red[3]));
}

// ---------- kernel 2: fused GEMM(x, W_eff^T) + sigmoid + sum_t attn*x -> ao (B,256)
// 1024 threads = 16 waves, each wave owns 16 output cols (lean VGPR -> 4 waves/SIMD).
// x staged fp32->fp16 into a single 16KB swizzled LDS buffer; 2-chunk-deep reg
// prefetch kept alive across raw s_barriers (no vmcnt drain).
__global__ __launch_bounds__(1024, 4) void attn_kernel(
    const float* __restrict__ x,          // (B, T, D)
    const _Float16* __restrict__ Weff,    // (256, 256) row-major [e][k]
    const float* __restrict__ beff,       // (256)
    float* __restrict__ ao)               // (B, 256)
{
    const int b    = blockIdx.x;
    const int tid  = threadIdx.x;          // 0..1023
    const int wave = tid >> 6;             // 0..15
    const int lane = tid & 63;
    const int l15  = lane & 15;
    const int lq   = lane >> 4;

    __shared__ _Float16 xs[TCHUNK * 256];  // 16 KB, swizzle: byte ^= (row&7)<<4
    char* xsb = reinterpret_cast<char*>(xs);

    // B fragments: wave's 16 cols, layout verified in round 1.
    const int col = wave*16 + l15;
    f16x8 bfrag[8];
    #pragma unroll
    for (int ks = 0; ks < 8; ++ks)
        bfrag[ks] = *reinterpret_cast<const f16x8*>(&Weff[col*256 + ks*32 + lq*8]);
    const float bcol = beff[col];

    const float* xb = x + (size_t)b * T_SZ * D_SZ;

    // staging: thread covers row = tid>>5 (0..31), 8 floats at col (tid&31)*8
    const int srow = tid >> 5;
    const int scg  = tid & 31;
    const float* srcp = xb + (size_t)srow * 256 + scg * 8;
    const int swb = (srow*512 + scg*16) ^ ((srow & 7) << 4);

    #define LOADC(R, c)                                                            \
        {                                                                          \
            const float* p = srcp + (size_t)(c) * (TCHUNK * D_SZ);                 \
            R##0 = *reinterpret_cast<const f32x4*>(p);                             \
            R##1 = *reinterpret_cast<const f32x4*>(p + 4);                         \
        }

    #define WRITE(R)                                                               \
        {                                                                          \
            f16x8 h;                                                               \
            h[0] = (_Float16)R##0[0]; h[1] = (_Float16)R##0[1];                    \
            h[2] = (_Float16)R##0[2]; h[3] = (_Float16)R##0[3];                    \
            h[4] = (_Float16)R##1[0]; h[5] = (_Float16)R##1[1];                    \
            h[6] = (_Float16)R##1[2]; h[7] = (_Float16)R##1[3];                    \
            *reinterpret_cast<f16x8*>(xsb + swb) = h;                              \
        }

    // lgkm drain (my LDS ops done) -> barrier; does NOT drain vmcnt (prefetch lives)
    #define SYNC()                                                                 \
        {                                                                          \
            asm volatile("s_waitcnt lgkmcnt(0)" ::: "memory");                     \
            __builtin_amdgcn_sched_barrier(0);                                     \
            __builtin_amdgcn_s_barrier();                                          \
        }

    #define COMPUTE()                                                              \
        {                                                                          \
            _Pragma("unroll")                                                      \
            for (int rt = 0; rt < 2; ++rt) {                                       \
                const int arow  = rt*16 + l15;                                     \
                const int aswz  = (arow & 7) << 4;                                 \
                const int abase = arow * 512;                                      \
                f32x4 acc = {0.f, 0.f, 0.f, 0.f};                                  \
                _Pragma("unroll")                                                  \
                for (int ks = 0; ks < 8; ++ks) {                                   \
                    int ab = abase + ((ks*64 + lq*16) ^ aswz);                     \
                    f16x8 a = *reinterpret_cast<const f16x8*>(xsb + ab);           \
                    acc = __builtin_amdgcn_mfma_f32_16x16x32_f16(                  \
                        a, bfrag[ks], acc, 0, 0, 0);                               \
                }                                                                  \
                _Pragma("unroll")                                                  \
                for (int r = 0; r < 4; ++r) {                                      \
                    int row = rt*16 + lq*4 + r;                                    \
                    float s = acc[r] + bcol;                                       \
                    float attn = __builtin_amdgcn_rcpf(1.f + __expf(-s));          \
                    int cb = (row*512 + col*2) ^ ((row & 7) << 4);                 \
                    float xv = (float)*reinterpret_cast<const _Float16*>(xsb + cb);\
                    ao_acc = fmaf(attn, xv, ao_acc);                               \
                }                                                                  \
            }                                                                      \
        }

    float ao_acc = 0.f;
    f32x4 sA0, sA1, sB0, sB1;

    LOADC(sA, 0);
    LOADC(sB, 1);

    for (int c = 0; c < NCHUNK; c += 2) {
        WRITE(sA);                       // compiler waits vmcnt for sA only
        SYNC();                          // chunk c visible to all waves
        if (c + 2 < NCHUNK) LOADC(sA, c + 2);
        COMPUTE();                       // chunk c
        SYNC();                          // all reads of chunk c done
        WRITE(sB);
        SYNC();                          // chunk c+1 visible
        if (c + 3 < NCHUNK) LOADC(sB, c + 3);
        COMPUTE();                       // chunk c+1
        SYNC();
    }

    // lanes {l15, lq=0..3} share one col: reduce across lq
    ao_acc += __shfl_xor(ao_acc, 16, 64);
    ao_acc += __shfl_xor(ao_acc, 32, 64);
    if (lq == 0) ao[b*256 + col] = ao_acc;

    #undef LOADC
    #undef WRITE
    #undef SYNC
    #undef COMPUTE
}

// ---------- kernel 3: LSTM cell (h0=c0=0 => f gate dead, W_hh dead)
__global__ __launch_bounds__(256) void lstm_kernel(
    const float* __restrict__ ao,        // (B, 256)
    const float* __restrict__ Wih,       // (1024, 256)
    const float* __restrict__ bih,       // (1024)
    const float* __restrict__ bhh,       // (1024)
    float* __restrict__ out)             // h (B*256) | h (B*256) | c (B*256)
{
    int b = blockIdx.x;    // 512
    int j = threadIdx.x;   // 256
    __shared__ float a[256];
    a[j] = ao[b*256 + j];
    __syncthreads();

    float gi = bih[j]       + bhh[j];
    float gg = bih[512 + j] + bhh[512 + j];
    float go = bih[768 + j] + bhh[768 + j];
    const float* wi = Wih + (size_t)j * 256;
    const float* wg = Wih + (size_t)(512 + j) * 256;
    const float* wo = Wih + (size_t)(768 + j) * 256;
    #pragma unroll 4
    for (int k = 0; k < 256; k += 4) {
        f32x4 w1 = *reinterpret_cast<const f32x4*>(wi + k);
        f32x4 w2 = *reinterpret_cast<const f32x4*>(wg + k);
        f32x4 w3 = *reinterpret_cast<const f32x4*>(wo + k);
        #pragma unroll
        for (int q = 0; q < 4; ++q) {
            float av = a[k + q];
            gi = fmaf(w1[q], av, gi);
            gg = fmaf(w2[q], av, gg);
            go = fmaf(w3[q], av, go);
        }
    }
    float ig = 1.f / (1.f + __expf(-gi));
    float g  = tanhf(gg);
    float og = 1.f / (1.f + __expf(-go));
    float cc = ig * g;
    float hh = og * tanhf(cc);
    out[          b*256 + j] = hh;
    out[131072 +  b*256 + j] = hh;
    out[262144 +  b*256 + j] = cc;
}

extern "C" void kernel_launch(void* const* d_in, const int* in_sizes, int n_in,
                              void* d_out, int out_size, void* d_ws, size_t ws_size,
                              hipStream_t stream) {
    const float* x    = (const float*)d_in[0];
    const float* Wi   = (const float*)d_in[1];
    const float* bi   = (const float*)d_in[2];
    // d_in[3] = Wh (dead: h0 = 0)
    const float* bh   = (const float*)d_in[4];
    const float* Wa   = (const float*)d_in[5];
    const float* ba   = (const float*)d_in[6];
    const float* W_ih = (const float*)d_in[7];
    const float* b_ih = (const float*)d_in[8];
    // d_in[9] = W_hh (dead: h0 = 0)
    const float* b_hh = (const float*)d_in[10];

    char* ws = (char*)d_ws;
    _Float16* Weff = (_Float16*)ws;                  // 128 KB
    float*    beff = (float*)(ws + 128*1024);        // 1 KB
    float*    ao   = (float*)(ws + 132*1024);        // 512 KB

    prep_kernel<<<256, 256, 0, stream>>>(Wa, Wi, bi, bh, ba, Weff, beff);
    attn_kernel<<<B_SZ, 1024, 0, stream>>>(x, Weff, beff, ao);
    lstm_kernel<<<B_SZ, 256, 0, stream>>>(ao, W_ih, b_ih, b_hh, (float*)d_out);
}

// Round 4
// 264.806 us; speedup vs baseline: 1.5892x; 1.1141x over previous
//
#include <hip/hip_runtime.h>
#include <hip/hip_bf16.h>

typedef _Float16 f16x8 __attribute__((ext_vector_type(8)));
typedef float    f32x4 __attribute__((ext_vector_type(4)));

#define B_SZ 512
#define T_SZ 2048
#define D_SZ 256
#define TCHUNK 16
#define NCHUNK (T_SZ / TCHUNK)   // 128

// ---------- kernel 1: W_eff[e,k] = sum_d Wa[e,d]*Wi[d,k];  b_eff[e] = Wa[e,:]@(bi+bh) + ba[e]
__global__ __launch_bounds__(256) void prep_kernel(
    const float* __restrict__ Wa, const float* __restrict__ Wi,
    const float* __restrict__ bi, const float* __restrict__ bh,
    const float* __restrict__ ba,
    _Float16* __restrict__ Weff, float* __restrict__ beff)
{
    int e = blockIdx.x;      // output row (256)
    int d = threadIdx.x;     // output col (256)
    float a0 = 0.f, a1 = 0.f, a2 = 0.f, a3 = 0.f;
    #pragma unroll 4
    for (int k = 0; k < 256; k += 4) {
        a0 = fmaf(Wa[e*256 + k    ], Wi[(k    )*256 + d], a0);
        a1 = fmaf(Wa[e*256 + k + 1], Wi[(k + 1)*256 + d], a1);
        a2 = fmaf(Wa[e*256 + k + 2], Wi[(k + 2)*256 + d], a2);
        a3 = fmaf(Wa[e*256 + k + 3], Wi[(k + 3)*256 + d], a3);
    }
    Weff[e*256 + d] = (_Float16)((a0 + a1) + (a2 + a3));

    __shared__ float red[4];
    float s = Wa[e*256 + d] * (bi[d] + bh[d]);
    s += __shfl_down(s, 32, 64);
    s += __shfl_down(s, 16, 64);
    s += __shfl_down(s,  8, 64);
    s += __shfl_down(s,  4, 64);
    s += __shfl_down(s,  2, 64);
    s += __shfl_down(s,  1, 64);
    if ((d & 63) == 0) red[d >> 6] = s;
    __syncthreads();
    if (d == 0) beff[e] = ba[e] + ((red[0] + red[1]) + (red[2] + red[3]));
}

// ---------- kernel 2: fused GEMM(x, W_eff^T) + sigmoid + sum_t attn*x -> ao (B,256)
// 512 threads = 8 waves; each wave owns 32 output cols (one A-fragment read feeds
// two MFMAs -> LDS read amplification 4:1 instead of 8:1). Lean VGPR (~110) under
// __launch_bounds__(512,4) -> 2 blocks/CU; the two blocks' barrier phases interleave.
// x staged fp32->fp16 into one 8 KB swizzled LDS buffer, 2-chunk-deep reg prefetch
// kept alive across raw s_barriers (lgkmcnt-only sync, vmcnt never drained).
__global__ __launch_bounds__(512, 4) void attn_kernel(
    const float* __restrict__ x,          // (B, T, D)
    const _Float16* __restrict__ Weff,    // (256, 256) row-major [e][k]
    const float* __restrict__ beff,       // (256)
    float* __restrict__ ao)               // (B, 256)
{
    const int b    = blockIdx.x;
    const int tid  = threadIdx.x;          // 0..511
    const int wave = tid >> 6;             // 0..7
    const int lane = tid & 63;
    const int l15  = lane & 15;
    const int lq   = lane >> 4;

    __shared__ _Float16 xs[TCHUNK * 256];  // 8 KB, swizzle: byte ^= (row&7)<<4
    char* xsb = reinterpret_cast<char*>(xs);

    // B fragments: wave's 32 cols = two 16-col tiles (layout verified in round 1)
    const int col0 = wave*32 + l15;
    const int col1 = col0 + 16;
    f16x8 bfA[8], bfB[8];
    #pragma unroll
    for (int ks = 0; ks < 8; ++ks) {
        bfA[ks] = *reinterpret_cast<const f16x8*>(&Weff[col0*256 + ks*32 + lq*8]);
        bfB[ks] = *reinterpret_cast<const f16x8*>(&Weff[col1*256 + ks*32 + lq*8]);
    }
    const float bc0 = beff[col0];
    const float bc1 = beff[col1];

    const float* xb = x + (size_t)b * T_SZ * D_SZ;

    // staging: thread covers row = tid>>5 (0..15), 8 floats at col (tid&31)*8
    const int srow = tid >> 5;
    const int scg  = tid & 31;
    const float* srcp = xb + (size_t)srow * 256 + scg * 8;
    const int swb = (srow*512 + scg*16) ^ ((srow & 7) << 4);

    #define LOADC(R, c)                                                            \
        {                                                                          \
            const float* p = srcp + (size_t)(c) * (TCHUNK * D_SZ);                 \
            R##0 = *reinterpret_cast<const f32x4*>(p);                             \
            R##1 = *reinterpret_cast<const f32x4*>(p + 4);                         \
        }

    #define WRITE(R)                                                               \
        {                                                                          \
            f16x8 h;                                                               \
            h[0] = (_Float16)R##0[0]; h[1] = (_Float16)R##0[1];                    \
            h[2] = (_Float16)R##0[2]; h[3] = (_Float16)R##0[3];                    \
            h[4] = (_Float16)R##1[0]; h[5] = (_Float16)R##1[1];                    \
            h[6] = (_Float16)R##1[2]; h[7] = (_Float16)R##1[3];                    \
            *reinterpret_cast<f16x8*>(xsb + swb) = h;                              \
        }

    // lgkm drain (my LDS ops done) -> barrier; does NOT drain vmcnt (prefetch lives)
    #define SYNC()                                                                 \
        {                                                                          \
            asm volatile("s_waitcnt lgkmcnt(0)" ::: "memory");                     \
            __builtin_amdgcn_sched_barrier(0);                                     \
            __builtin_amdgcn_s_barrier();                                          \
        }

    #define COMPUTE()                                                              \
        {                                                                          \
            const int arow  = l15;                                                 \
            const int aswz  = (arow & 7) << 4;                                     \
            const int abase = arow * 512;                                          \
            f32x4 acc0 = {0.f, 0.f, 0.f, 0.f};                                     \
            f32x4 acc1 = {0.f, 0.f, 0.f, 0.f};                                     \
            _Pragma("unroll")                                                      \
            for (int ks = 0; ks < 8; ++ks) {                                       \
                int ab = abase + ((ks*64 + lq*16) ^ aswz);                         \
                f16x8 a = *reinterpret_cast<const f16x8*>(xsb + ab);               \
                acc0 = __builtin_amdgcn_mfma_f32_16x16x32_f16(a, bfA[ks], acc0, 0, 0, 0); \
                acc1 = __builtin_amdgcn_mfma_f32_16x16x32_f16(a, bfB[ks], acc1, 0, 0, 0); \
            }                                                                      \
            _Pragma("unroll")                                                      \
            for (int r = 0; r < 4; ++r) {                                          \
                int row  = lq*4 + r;                                               \
                int rswz = (row & 7) << 4;                                         \
                int rb   = row * 512;                                              \
                {                                                                  \
                    float s = acc0[r] + bc0;                                       \
                    float attn = __builtin_amdgcn_rcpf(1.f + __expf(-s));          \
                    float xv = (float)*reinterpret_cast<const _Float16*>(          \
                        xsb + rb + ((col0*2) ^ rswz));                             \
                    ao0 = fmaf(attn, xv, ao0);                                     \
                }                                                                  \
                {                                                                  \
                    float s = acc1[r] + bc1;                                       \
                    float attn = __builtin_amdgcn_rcpf(1.f + __expf(-s));          \
                    float xv = (float)*reinterpret_cast<const _Float16*>(          \
                        xsb + rb + ((col1*2) ^ rswz));                             \
                    ao1 = fmaf(attn, xv, ao1);                                     \
                }                                                                  \
            }                                                                      \
        }

    float ao0 = 0.f, ao1 = 0.f;
    f32x4 sA0, sA1, sB0, sB1;

    LOADC(sA, 0);
    LOADC(sB, 1);

    for (int c = 0; c < NCHUNK; c += 2) {
        WRITE(sA);                       // compiler waits vmcnt for sA only
        SYNC();                          // chunk c visible to all waves
        if (c + 2 < NCHUNK) LOADC(sA, c + 2);
        COMPUTE();                       // chunk c
        SYNC();                          // all reads of chunk c done
        WRITE(sB);
        SYNC();                          // chunk c+1 visible
        if (c + 3 < NCHUNK) LOADC(sB, c + 3);
        COMPUTE();                       // chunk c+1
        SYNC();
    }

    // lanes {l15, lq=0..3} share one col: reduce across lq
    ao0 += __shfl_xor(ao0, 16, 64);
    ao0 += __shfl_xor(ao0, 32, 64);
    ao1 += __shfl_xor(ao1, 16, 64);
    ao1 += __shfl_xor(ao1, 32, 64);
    if (lq == 0) {
        ao[b*256 + col0] = ao0;
        ao[b*256 + col1] = ao1;
    }

    #undef LOADC
    #undef WRITE
    #undef SYNC
    #undef COMPUTE
}

// ---------- kernel 3: LSTM cell (h0=c0=0 => f gate dead, W_hh dead)
__global__ __launch_bounds__(256) void lstm_kernel(
    const float* __restrict__ ao,        // (B, 256)
    const float* __restrict__ Wih,       // (1024, 256)
    const float* __restrict__ bih,       // (1024)
    const float* __restrict__ bhh,       // (1024)
    float* __restrict__ out)             // h (B*256) | h (B*256) | c (B*256)
{
    int b = blockIdx.x;    // 512
    int j = threadIdx.x;   // 256
    __shared__ float a[256];
    a[j] = ao[b*256 + j];
    __syncthreads();

    float gi = bih[j]       + bhh[j];
    float gg = bih[512 + j] + bhh[512 + j];
    float go = bih[768 + j] + bhh[768 + j];
    const float* wi = Wih + (size_t)j * 256;
    const float* wg = Wih + (size_t)(512 + j) * 256;
    const float* wo = Wih + (size_t)(768 + j) * 256;
    #pragma unroll 4
    for (int k = 0; k < 256; k += 4) {
        f32x4 w1 = *reinterpret_cast<const f32x4*>(wi + k);
        f32x4 w2 = *reinterpret_cast<const f32x4*>(wg + k);
        f32x4 w3 = *reinterpret_cast<const f32x4*>(wo + k);
        #pragma unroll
        for (int q = 0; q < 4; ++q) {
            float av = a[k + q];
            gi = fmaf(w1[q], av, gi);
            gg = fmaf(w2[q], av, gg);
            go = fmaf(w3[q], av, go);
        }
    }
    float ig = 1.f / (1.f + __expf(-gi));
    float g  = tanhf(gg);
    float og = 1.f / (1.f + __expf(-go));
    float cc = ig * g;
    float hh = og * tanhf(cc);
    out[          b*256 + j] = hh;
    out[131072 +  b*256 + j] = hh;
    out[262144 +  b*256 + j] = cc;
}

extern "C" void kernel_launch(void* const* d_in, const int* in_sizes, int n_in,
                              void* d_out, int out_size, void* d_ws, size_t ws_size,
                              hipStream_t stream) {
    const float* x    = (const float*)d_in[0];
    const float* Wi   = (const float*)d_in[1];
    const float* bi   = (const float*)d_in[2];
    // d_in[3] = Wh (dead: h0 = 0)
    const float* bh   = (const float*)d_in[4];
    const float* Wa   = (const float*)d_in[5];
    const float* ba   = (const float*)d_in[6];
    const float* W_ih = (const float*)d_in[7];
    const float* b_ih = (const float*)d_in[8];
    // d_in[9] = W_hh (dead: h0 = 0)
    const float* b_hh = (const float*)d_in[10];

    char* ws = (char*)d_ws;
    _Float16* Weff = (_Float16*)ws;                  // 128 KB
    float*    beff = (float*)(ws + 128*1024);        // 1 KB
    float*    ao   = (float*)(ws + 132*1024);        // 512 KB

    prep_kernel<<<256, 256, 0, stream>>>(Wa, Wi, bi, bh, ba, Weff, beff);
    attn_kernel<<<B_SZ, 512, 0, stream>>>(x, Weff, beff, ao);
    lstm_kernel<<<B_SZ, 256, 0, stream>>>(ao, W_ih, b_ih, b_hh, (float*)d_out);
}

// Round 5
// 264.413 us; speedup vs baseline: 1.5916x; 1.0015x over previous
//
#include <hip/hip_runtime.h>
#include <hip/hip_bf16.h>

typedef _Float16 f16x8 __attribute__((ext_vector_type(8)));
typedef _Float16 f16x4 __attribute__((ext_vector_type(4)));
typedef float    f32x4 __attribute__((ext_vector_type(4)));

#define B_SZ 512
#define T_SZ 2048
#define D_SZ 256
#define TCHUNK 16
#define NCHUNK (T_SZ / TCHUNK)   // 128

// ---------- kernel 1: W_eff[e,k] = sum_d Wa[e,d]*Wi[d,k];  b_eff[e] = Wa[e,:]@(bi+bh) + ba[e]
__global__ __launch_bounds__(256) void prep_kernel(
    const float* __restrict__ Wa, const float* __restrict__ Wi,
    const float* __restrict__ bi, const float* __restrict__ bh,
    const float* __restrict__ ba,
    _Float16* __restrict__ Weff, float* __restrict__ beff)
{
    int e = blockIdx.x;      // output row (256)
    int d = threadIdx.x;     // output col (256)
    float a0 = 0.f, a1 = 0.f, a2 = 0.f, a3 = 0.f;
    #pragma unroll 4
    for (int k = 0; k < 256; k += 4) {
        a0 = fmaf(Wa[e*256 + k    ], Wi[(k    )*256 + d], a0);
        a1 = fmaf(Wa[e*256 + k + 1], Wi[(k + 1)*256 + d], a1);
        a2 = fmaf(Wa[e*256 + k + 2], Wi[(k + 2)*256 + d], a2);
        a3 = fmaf(Wa[e*256 + k + 3], Wi[(k + 3)*256 + d], a3);
    }
    Weff[e*256 + d] = (_Float16)((a0 + a1) + (a2 + a3));

    __shared__ float red[4];
    float s = Wa[e*256 + d] * (bi[d] + bh[d]);
    s += __shfl_down(s, 32, 64);
    s += __shfl_down(s, 16, 64);
    s += __shfl_down(s,  8, 64);
    s += __shfl_down(s,  4, 64);
    s += __shfl_down(s,  2, 64);
    s += __shfl_down(s,  1, 64);
    if ((d & 63) == 0) red[d >> 6] = s;
    __syncthreads();
    if (d == 0) beff[e] = ba[e] + ((red[0] + red[1]) + (red[2] + red[3]));
}

// ---------- kernel 2: fused GEMM + sigmoid + sum_t attn*x -> ao (B,256)
// 8 waves x 32 cols. SWAPPED MFMA operands: acc = mfma(Weff_frag, x_frag) gives
// S^T (col=t=l15, row=e=lq*4+r) -> epilogue x re-read becomes one ds_read_b64 of
// 4 consecutive fp16 per col-tile (bank-clean) instead of 8 conflicted scalars.
// Double-buffered 2x8KB LDS -> ONE barrier per chunk. 2-chunk reg prefetch, vmcnt
// never drained by sync (lgkmcnt-only).
__global__ __launch_bounds__(512, 4) void attn_kernel(
    const float* __restrict__ x,          // (B, T, D)
    const _Float16* __restrict__ Weff,    // (256, 256) row-major [e][k]
    const float* __restrict__ beff,       // (256)
    float* __restrict__ ao)               // (B, 256)
{
    const int b    = blockIdx.x;
    const int tid  = threadIdx.x;          // 0..511
    const int wave = tid >> 6;             // 0..7
    const int lane = tid & 63;
    const int l15  = lane & 15;
    const int lq   = lane >> 4;

    __shared__ _Float16 xs[2][TCHUNK * 256];  // 2 x 8 KB, swizzle: byte ^= (row&7)<<4
    char* xsb0 = reinterpret_cast<char*>(&xs[0][0]);
    char* xsb1 = reinterpret_cast<char*>(&xs[1][0]);

    // Weff fragments (A-operand after swap): lane holds Weff[e = tile_base + l15][k = ks*32 + lq*8 + i]
    const int col0 = wave*32 + l15;
    const int col1 = col0 + 16;
    f16x8 bfA[8], bfB[8];
    #pragma unroll
    for (int ks = 0; ks < 8; ++ks) {
        bfA[ks] = *reinterpret_cast<const f16x8*>(&Weff[col0*256 + ks*32 + lq*8]);
        bfB[ks] = *reinterpret_cast<const f16x8*>(&Weff[col1*256 + ks*32 + lq*8]);
    }
    // bias per accumulator slot: e = wave*32 (+16) + lq*4 + r
    const f32x4 bcA = *reinterpret_cast<const f32x4*>(&beff[wave*32 + lq*4]);
    const f32x4 bcB = *reinterpret_cast<const f32x4*>(&beff[wave*32 + 16 + lq*4]);

    const float* xb = x + (size_t)b * T_SZ * D_SZ;

    // staging: thread covers row = tid>>5 (0..15), 8 floats at col (tid&31)*8
    const int srow = tid >> 5;
    const int scg  = tid & 31;
    const float* srcp = xb + (size_t)srow * 256 + scg * 8;
    const int swb = (srow*512 + scg*16) ^ ((srow & 7) << 4);

    #define LOADC(R, c)                                                            \
        {                                                                          \
            const float* p = srcp + (size_t)(c) * (TCHUNK * D_SZ);                 \
            R##0 = *reinterpret_cast<const f32x4*>(p);                             \
            R##1 = *reinterpret_cast<const f32x4*>(p + 4);                         \
        }

    #define WRITE(BUF, R)                                                          \
        {                                                                          \
            f16x8 h;                                                               \
            h[0] = (_Float16)R##0[0]; h[1] = (_Float16)R##0[1];                    \
            h[2] = (_Float16)R##0[2]; h[3] = (_Float16)R##0[3];                    \
            h[4] = (_Float16)R##1[0]; h[5] = (_Float16)R##1[1];                    \
            h[6] = (_Float16)R##1[2]; h[7] = (_Float16)R##1[3];                    \
            *reinterpret_cast<f16x8*>((BUF) + swb) = h;                            \
        }

    // lgkm drain (my LDS ops done) -> barrier; does NOT drain vmcnt (prefetch lives)
    #define SYNC()                                                                 \
        {                                                                          \
            asm volatile("s_waitcnt lgkmcnt(0)" ::: "memory");                     \
            __builtin_amdgcn_sched_barrier(0);                                     \
            __builtin_amdgcn_s_barrier();                                          \
        }

    #define COMPUTE(BUF)                                                           \
        {                                                                          \
            const int aswz  = (l15 & 7) << 4;                                      \
            const int abase = l15 * 512;                                           \
            f32x4 acc0 = {0.f, 0.f, 0.f, 0.f};                                     \
            f32x4 acc1 = {0.f, 0.f, 0.f, 0.f};                                     \
            _Pragma("unroll")                                                      \
            for (int ks = 0; ks < 8; ++ks) {                                       \
                int ab = abase + ((ks*64 + lq*16) ^ aswz);                         \
                f16x8 a = *reinterpret_cast<const f16x8*>((BUF) + ab);             \
                acc0 = __builtin_amdgcn_mfma_f32_16x16x32_f16(bfA[ks], a, acc0, 0, 0, 0); \
                acc1 = __builtin_amdgcn_mfma_f32_16x16x32_f16(bfB[ks], a, acc1, 0, 0, 0); \
            }                                                                      \
            /* epilogue: lane has t = l15, e = wave*32 (+16) + lq*4 + r          */ \
            int eb0 = abase + (((wave*64      ) + lq*8) ^ aswz);                   \
            int eb1 = abase + (((wave*64 + 32 ) + lq*8) ^ aswz);                   \
            f16x4 xq0 = *reinterpret_cast<const f16x4*>((BUF) + eb0);              \
            f16x4 xq1 = *reinterpret_cast<const f16x4*>((BUF) + eb1);              \
            _Pragma("unroll")                                                      \
            for (int r = 0; r < 4; ++r) {                                          \
                {                                                                  \
                    float s = acc0[r] + bcA[r];                                    \
                    float attn = __builtin_amdgcn_rcpf(1.f + __expf(-s));          \
                    ao0[r] = fmaf(attn, (float)xq0[r], ao0[r]);                    \
                }                                                                  \
                {                                                                  \
                    float s = acc1[r] + bcB[r];                                    \
                    float attn = __builtin_amdgcn_rcpf(1.f + __expf(-s));          \
                    ao1[r] = fmaf(attn, (float)xq1[r], ao1[r]);                    \
                }                                                                  \
            }                                                                      \
        }

    f32x4 ao0 = {0.f, 0.f, 0.f, 0.f};
    f32x4 ao1 = {0.f, 0.f, 0.f, 0.f};
    f32x4 sA0, sA1, sB0, sB1;

    LOADC(sA, 0);
    LOADC(sB, 1);

    for (int c = 0; c < NCHUNK; c += 2) {
        WRITE(xsb0, sA);                 // compiler waits vmcnt for sA only
        SYNC();                          // chunk c visible; old xsb0 reads were pre-barrier
        if (c + 2 < NCHUNK) LOADC(sA, c + 2);
        COMPUTE(xsb0);                   // chunk c
        WRITE(xsb1, sB);                 // other buffer: safe while others compute xsb0
        SYNC();                          // chunk c+1 visible
        if (c + 3 < NCHUNK) LOADC(sB, c + 3);
        COMPUTE(xsb1);                   // chunk c+1
    }

    // sum over t: reduce across l15 within each lq group
    #pragma unroll
    for (int m = 1; m <= 8; m <<= 1) {
        #pragma unroll
        for (int r = 0; r < 4; ++r) {
            ao0[r] += __shfl_xor(ao0[r], m, 64);
            ao1[r] += __shfl_xor(ao1[r], m, 64);
        }
    }
    if (l15 == 0) {
        *reinterpret_cast<f32x4*>(&ao[b*256 + wave*32 +      lq*4]) = ao0;
        *reinterpret_cast<f32x4*>(&ao[b*256 + wave*32 + 16 + lq*4]) = ao1;
    }

    #undef LOADC
    #undef WRITE
    #undef SYNC
    #undef COMPUTE
}

// ---------- kernel 3: LSTM cell (h0=c0=0 => f gate dead, W_hh dead)
__global__ __launch_bounds__(256) void lstm_kernel(
    const float* __restrict__ ao,        // (B, 256)
    const float* __restrict__ Wih,       // (1024, 256)
    const float* __restrict__ bih,       // (1024)
    const float* __restrict__ bhh,       // (1024)
    float* __restrict__ out)             // h (B*256) | h (B*256) | c (B*256)
{
    int b = blockIdx.x;    // 512
    int j = threadIdx.x;   // 256
    __shared__ float a[256];
    a[j] = ao[b*256 + j];
    __syncthreads();

    float gi = bih[j]       + bhh[j];
    float gg = bih[512 + j] + bhh[512 + j];
    float go = bih[768 + j] + bhh[768 + j];
    const float* wi = Wih + (size_t)j * 256;
    const float* wg = Wih + (size_t)(512 + j) * 256;
    const float* wo = Wih + (size_t)(768 + j) * 256;
    #pragma unroll 4
    for (int k = 0; k < 256; k += 4) {
        f32x4 w1 = *reinterpret_cast<const f32x4*>(wi + k);
        f32x4 w2 = *reinterpret_cast<const f32x4*>(wg + k);
        f32x4 w3 = *reinterpret_cast<const f32x4*>(wo + k);
        #pragma unroll
        for (int q = 0; q < 4; ++q) {
            float av = a[k + q];
            gi = fmaf(w1[q], av, gi);
            gg = fmaf(w2[q], av, gg);
            go = fmaf(w3[q], av, go);
        }
    }
    float ig = 1.f / (1.f + __expf(-gi));
    float g  = tanhf(gg);
    float og = 1.f / (1.f + __expf(-go));
    float cc = ig * g;
    float hh = og * tanhf(cc);
    out[          b*256 + j] = hh;
    out[131072 +  b*256 + j] = hh;
    out[262144 +  b*256 + j] = cc;
}

extern "C" void kernel_launch(void* const* d_in, const int* in_sizes, int n_in,
                              void* d_out, int out_size, void* d_ws, size_t ws_size,
                              hipStream_t stream) {
    const float* x    = (const float*)d_in[0];
    const float* Wi   = (const float*)d_in[1];
    const float* bi   = (const float*)d_in[2];
    // d_in[3] = Wh (dead: h0 = 0)
    const float* bh   = (const float*)d_in[4];
    const float* Wa   = (const float*)d_in[5];
    const float* ba   = (const float*)d_in[6];
    const float* W_ih = (const float*)d_in[7];
    const float* b_ih = (const float*)d_in[8];
    // d_in[9] = W_hh (dead: h0 = 0)
    const float* b_hh = (const float*)d_in[10];

    char* ws = (char*)d_ws;
    _Float16* Weff = (_Float16*)ws;                  // 128 KB
    float*    beff = (float*)(ws + 128*1024);        // 1 KB
    float*    ao   = (float*)(ws + 132*1024);        // 512 KB

    prep_kernel<<<256, 256, 0, stream>>>(Wa, Wi, bi, bh, ba, Weff, beff);
    attn_kernel<<<B_SZ, 512, 0, stream>>>(x, Weff, beff, ao);
    lstm_kernel<<<B_SZ, 256, 0, stream>>>(ao, W_ih, b_ih, b_hh, (float*)d_out);
}